// Round 4
// baseline (177.183 us; speedup 1.0000x reference)
//
#include <hip/hip_runtime.h>
#include <math.h>

#define T_LEN 256
#define HID 10

// ds_swizzle compile-time pattern (BitMode): src = ((lane & and) | or) ^ xor
// broadcast lane TI within each 16-lane group: and=0x10 (keep group bit), or=TI
template <int PAT>
__device__ __forceinline__ float swz(float v) {
    return __int_as_float(__builtin_amdgcn_ds_swizzle(__float_as_int(v), PAT));
}

// setup-only accurate softplus
__device__ __forceinline__ float softplus_f(float x) {
    return fmaxf(x, 0.0f) + log1pf(expf(-fabsf(x)));
}
__device__ __forceinline__ float samp(const float* mu, const float* rho,
                                      const float* eps, int i) {
    return mu[i] + softplus_f(rho[i]) * eps[i];
}

// sigmoid = rcp(1 + 2^(-log2e*x)) : mul, exp, add, rcp
__device__ __forceinline__ float fast_sigmoid(float x) {
    float e = __builtin_amdgcn_exp2f(-1.442695040888963f * x);
    return __builtin_amdgcn_rcpf(1.0f + e);
}
// tanh = 1 - 2*rcp(2^(2*log2e*x) + 1) : mul, exp, add, rcp, fma
__device__ __forceinline__ float fast_tanh(float x) {
    float e = __builtin_amdgcn_exp2f(2.885390081777927f * x);
    return fmaf(-2.0f, __builtin_amdgcn_rcpf(e + 1.0f), 1.0f);
}

// gates + state update for one element, fully scalar, bias folded into first fma
#define GATES(HV, XT, CC, HK)                                            \
    {                                                                    \
        float gi = fmaf((XT), wih[0], bs[0]);                            \
        float gf = fmaf((XT), wih[1], bs[1]);                            \
        float gg = fmaf((XT), wih[2], bs[2]);                            \
        float go = fmaf((XT), wih[3], bs[3]);                            \
        _Pragma("unroll")                                                \
        for (int j = 0; j < HID; ++j) {                                  \
            gi = fmaf(HV[j], whi[j], gi);                                \
            gf = fmaf(HV[j], whf[j], gf);                                \
            gg = fmaf(HV[j], whg[j], gg);                                \
            go = fmaf(HV[j], who[j], go);                                \
        }                                                                \
        float si = fast_sigmoid(gi);                                     \
        float sf = fast_sigmoid(gf);                                     \
        float tg = fast_tanh(gg);                                        \
        float so = fast_sigmoid(go);                                     \
        (CC) = fmaf(sf, (CC), si * tg);                                  \
        (HK) = so * fast_tanh(CC);                                       \
    }

#define TSTEP(TI)                                                        \
    {                                                                    \
        float4 hA0 = *(const float4*)(hbA);                              \
        float4 hA1 = *(const float4*)(hbA + 4);                          \
        float2 hA2 = *(const float2*)(hbA + 8);                          \
        float4 hB0 = *(const float4*)(hbB);                              \
        float4 hB1 = *(const float4*)(hbB + 4);                          \
        float2 hB2 = *(const float2*)(hbB + 8);                          \
        float xa = swz<((TI) << 5) | 0x10>(xcA);                         \
        float xb = swz<((TI) << 5) | 0x10>(xcB);                         \
        float hvA[HID] = {hA0.x, hA0.y, hA0.z, hA0.w,                    \
                          hA1.x, hA1.y, hA1.z, hA1.w, hA2.x, hA2.y};     \
        float hvB[HID] = {hB0.x, hB0.y, hB0.z, hB0.w,                    \
                          hB1.x, hB1.y, hB1.z, hB1.w, hB2.x, hB2.y};     \
        GATES(hvA, xa, cA, hkA);                                         \
        GATES(hvB, xb, cB, hkB);                                         \
        wrA[0] = hkA;                                                    \
        wrB[0] = hkB;                                                    \
    }

__global__ __launch_bounds__(256) void bayes_lstm_kernel(
    const float* __restrict__ x,
    const float* __restrict__ w_ih_mu, const float* __restrict__ w_ih_rho,
    const float* __restrict__ w_hh_mu, const float* __restrict__ w_hh_rho,
    const float* __restrict__ b_mu,    const float* __restrict__ b_rho,
    const float* __restrict__ eps_ih,  const float* __restrict__ eps_hh,
    const float* __restrict__ eps_b,
    const float* __restrict__ lin_w,   const float* __restrict__ lin_b,
    float* __restrict__ out)
{
    // 16 slots x 2 elements x 20 words (80B stride: 16B-aligned bases, write
    // conflicts <=2-way (free), group b128 broadcast reads bank-disjoint).
    __shared__ __align__(16) float hbuf[16 * 2 * 20];

    const int tid  = threadIdx.x;
    const int k    = tid & 15;           // hidden unit (active: k < 10)
    const int slot = tid >> 4;           // 0..15
    const int bA   = (blockIdx.x * 16 + slot) * 2;
    const int bB   = bA + 1;

    float* hbA = hbuf + (slot * 2 + 0) * 20;   // group-uniform read base
    float* hbB = hbuf + (slot * 2 + 1) * 20;
    float* wrA = hbA + k;                       // this lane's write addr
    float* wrB = hbB + k;

    // ---- sample weights (scalar arrays; zero for lanes 10..15) ----
    float whi[HID], whf[HID], whg[HID], who[HID];
    float wih[4] = {0.f, 0.f, 0.f, 0.f};
    float bs[4]  = {0.f, 0.f, 0.f, 0.f};
    float lw = 0.f;
#pragma unroll
    for (int j = 0; j < HID; ++j) { whi[j] = 0.f; whf[j] = 0.f; whg[j] = 0.f; who[j] = 0.f; }

    if (k < HID) {
        const int c0 = k, c1 = HID + k, c2 = 2 * HID + k, c3 = 3 * HID + k;
        wih[0] = samp(w_ih_mu, w_ih_rho, eps_ih, c0);
        wih[1] = samp(w_ih_mu, w_ih_rho, eps_ih, c1);
        wih[2] = samp(w_ih_mu, w_ih_rho, eps_ih, c2);
        wih[3] = samp(w_ih_mu, w_ih_rho, eps_ih, c3);
        bs[0]  = samp(b_mu, b_rho, eps_b, c0);
        bs[1]  = samp(b_mu, b_rho, eps_b, c1);
        bs[2]  = samp(b_mu, b_rho, eps_b, c2);
        bs[3]  = samp(b_mu, b_rho, eps_b, c3);
#pragma unroll
        for (int j = 0; j < HID; ++j) {
            whi[j] = samp(w_hh_mu, w_hh_rho, eps_hh, j * 4 * HID + c0);
            whf[j] = samp(w_hh_mu, w_hh_rho, eps_hh, j * 4 * HID + c1);
            whg[j] = samp(w_hh_mu, w_hh_rho, eps_hh, j * 4 * HID + c2);
            who[j] = samp(w_hh_mu, w_hh_rho, eps_hh, j * 4 * HID + c3);
        }
        lw = lin_w[k];
    }

    // zero h slots (all 16 lanes write; covers the 10 words reads touch)
    wrA[0] = 0.f;
    wrB[0] = 0.f;

    float cA = 0.f, cB = 0.f, hkA = 0.f, hkB = 0.f;
    const float* xrA = x + (size_t)bA * T_LEN;
    const float* xrB = x + (size_t)bB * T_LEN;
    float xcA = xrA[k];                  // chunk 0: lane k holds x[t=k]
    float xcB = xrB[k];

    for (int to = 0; to < 16; ++to) {
        float xnA = 0.f, xnB = 0.f;
        if (to < 15) {                   // prefetch next 16-step chunk
            xnA = xrA[(to + 1) * 16 + k];
            xnB = xrB[(to + 1) * 16 + k];
        }
        TSTEP(0)  TSTEP(1)  TSTEP(2)  TSTEP(3)
        TSTEP(4)  TSTEP(5)  TSTEP(6)  TSTEP(7)
        TSTEP(8)  TSTEP(9)  TSTEP(10) TSTEP(11)
        TSTEP(12) TSTEP(13) TSTEP(14) TSTEP(15)
        xcA = xnA; xcB = xnB;
    }

    // ---- linear head: lane k holds final h[k]; reduce over 16-lane group ----
    float pa = hkA * lw;                 // lanes >= 10 contribute 0
    float pb = hkB * lw;
    pa += __shfl_xor(pa, 1, 16);  pb += __shfl_xor(pb, 1, 16);
    pa += __shfl_xor(pa, 2, 16);  pb += __shfl_xor(pb, 2, 16);
    pa += __shfl_xor(pa, 4, 16);  pb += __shfl_xor(pb, 4, 16);
    pa += __shfl_xor(pa, 8, 16);  pb += __shfl_xor(pb, 8, 16);
    if (k == 0) {
        float b0 = lin_b[0];
        out[bA] = pa + b0;
        out[bB] = pb + b0;
    }
}

extern "C" void kernel_launch(void* const* d_in, const int* in_sizes, int n_in,
                              void* d_out, int out_size, void* d_ws, size_t ws_size,
                              hipStream_t stream) {
    const float* x        = (const float*)d_in[0];
    const float* w_ih_mu  = (const float*)d_in[1];
    const float* w_ih_rho = (const float*)d_in[2];
    const float* w_hh_mu  = (const float*)d_in[3];
    const float* w_hh_rho = (const float*)d_in[4];
    const float* b_mu     = (const float*)d_in[5];
    const float* b_rho    = (const float*)d_in[6];
    const float* eps_ih   = (const float*)d_in[7];
    const float* eps_hh   = (const float*)d_in[8];
    const float* eps_b    = (const float*)d_in[9];
    const float* lin_w    = (const float*)d_in[10];
    const float* lin_b    = (const float*)d_in[11];
    float* out = (float*)d_out;

    const int n_b = in_sizes[0] / T_LEN;     // 8192
    dim3 grid(n_b / 32), block(256);         // 16 slots x 2 elements per block
    hipLaunchKernelGGL(bayes_lstm_kernel, grid, block, 0, stream,
                       x, w_ih_mu, w_ih_rho, w_hh_mu, w_hh_rho, b_mu, b_rho,
                       eps_ih, eps_hh, eps_b, lin_w, lin_b, out);
}